// Round 1
// baseline (227.542 us; speedup 1.0000x reference)
//
#include <hip/hip_runtime.h>
#include <hip/hip_bf16.h>
#include <cstdint>
#include <cstddef>

#define C_N 100000
#define B_N 512
#define D_N 512

#define COS_M_F   0.87758256189037276f
#define SIN_M_F   0.47942553860420301f
#define THRESH_F  (-0.87758256189037276f)
#define MM_F      0.23971276930210150f
#define S_F       64.0f

typedef __attribute__((ext_vector_type(8))) short short8;
typedef __attribute__((ext_vector_type(4))) float f32x4;

__device__ __forceinline__ unsigned short f2bf(float f) {
  unsigned u = __float_as_uint(f);
  u = u + 0x7fffu + ((u >> 16) & 1u);
  return (unsigned short)(u >> 16);
}

__device__ __forceinline__ float wave_sum(float v) {
#pragma unroll
  for (int o = 32; o > 0; o >>= 1) v += __shfl_down(v, o, 64);
  return v;
}

// ---------------- kernel 1a: column sum-of-squares partials (d-split) ---------
#define JV (C_N / 4)       // 25000 float4 columns
#define DSPLIT 8
#define DCH (D_N / DSPLIT) // 64

__global__ void colnorm_part_k(const float* __restrict__ Kp, float4* __restrict__ part) {
  int j4 = blockIdx.x * blockDim.x + threadIdx.x;
  if (j4 >= JV) return;
  int db = blockIdx.y;
  const float4* Kv = (const float4*)Kp;
  float4 s = make_float4(0.f, 0.f, 0.f, 0.f);
  int d0 = db * DCH;
  for (int d = d0; d < d0 + DCH; ++d) {
    float4 v = Kv[(size_t)d * JV + j4];
    s.x += v.x * v.x; s.y += v.y * v.y; s.z += v.z * v.z; s.w += v.w * v.w;
  }
  part[(size_t)db * JV + j4] = s;
}

// ---------------- kernel 1b: finalize rsqrt ----------------------------------
__global__ void colnorm_fin_k(const float4* __restrict__ part, float4* __restrict__ cninv4) {
  int j4 = blockIdx.x * blockDim.x + threadIdx.x;
  if (j4 >= JV) return;
  float4 s = make_float4(0.f, 0.f, 0.f, 0.f);
#pragma unroll
  for (int db = 0; db < DSPLIT; ++db) {
    float4 v = part[(size_t)db * JV + j4];
    s.x += v.x; s.y += v.y; s.z += v.z; s.w += v.w;
  }
  float4 r;
  r.x = rsqrtf(s.x); r.y = rsqrtf(s.y); r.z = rsqrtf(s.z); r.w = rsqrtf(s.w);
  cninv4[j4] = r;
}

// ---------------- kernel 2: embedding row normalize -> bf16 ------------------
__global__ void embnorm_k(const float* __restrict__ emb, unsigned short* __restrict__ embn,
                          float* __restrict__ rinv) {
  int row = blockIdx.x;
  int t = threadIdx.x;  // 128 threads, one float4 each
  float4 v = ((const float4*)(emb + (size_t)row * D_N))[t];
  float ss = v.x * v.x + v.y * v.y + v.z * v.z + v.w * v.w;
  ss = wave_sum(ss);
  __shared__ float red[2];
  if ((t & 63) == 0) red[t >> 6] = ss;
  __syncthreads();
  float tot = red[0] + red[1];
  float ri = rsqrtf(tot);
  if (t == 0) rinv[row] = ri;
  ushort4 o;
  o.x = f2bf(v.x * ri); o.y = f2bf(v.y * ri); o.z = f2bf(v.z * ri); o.w = f2bf(v.w * ri);
  ((ushort4*)(embn + (size_t)row * D_N))[t] = o;
}

// ---------------- kernel 3: per-row target logit (f32, exact path) -----------
__global__ void target_k(const float* __restrict__ emb, const float* __restrict__ Kp,
                         const float* __restrict__ cninv, const float* __restrict__ rinv,
                         const int* __restrict__ labels,
                         float* __restrict__ target, float* __restrict__ ctm,
                         float* __restrict__ ft) {
  int row = blockIdx.x;
  int t = threadIdx.x;  // 256
  int lab = labels[row];
  float p = 0.f;
  for (int d = t; d < D_N; d += 256)
    p += emb[(size_t)row * D_N + d] * Kp[(size_t)d * C_N + lab];
  p = wave_sum(p);
  __shared__ float red[4];
  if ((t & 63) == 0) red[t >> 6] = p;
  __syncthreads();
  if (t == 0) {
    float dot = red[0] + red[1] + red[2] + red[3];
    float tg = dot * rinv[row] * cninv[lab];
    tg = fminf(fmaxf(tg, -1.f), 1.f);
    float st = sqrtf(fmaxf(1.f - tg * tg, 0.f));
    float cm = tg * COS_M_F - st * SIN_M_F;
    float f = (tg > THRESH_F) ? cm : (tg - MM_F);
    target[row] = tg;
    ctm[row] = cm;
    ft[row] = f;
  }
}

// ---------------- kernel 4: new_t reduction ----------------------------------
__global__ void newt_k(const float* __restrict__ target, const float* __restrict__ t_in,
                       float* __restrict__ newt) {
  int t = threadIdx.x;  // 512
  float v = target[t];
  v = wave_sum(v);
  __shared__ float red[8];
  if ((t & 63) == 0) red[t >> 6] = v;
  __syncthreads();
  if (t == 0) {
    float s = 0.f;
#pragma unroll
    for (int i = 0; i < 8; ++i) s += red[i];
    *newt = 0.01f * (s / (float)B_N) + 0.99f * t_in[0];
  }
}

// ---------------- kernel 5: MFMA GEMM + fused epilogue -----------------------
// BM=512 (all rows -> K read exactly once from HBM), BN=64, BK=32.
// 512 threads = 8 waves arranged 4(M) x 2(N); wave tile 128x32 = 8x2 frags of 16x16.
#define BN 64
#define BK 32
#define PAD 40  // LDS row stride in bf16 elems; 80B rows (16B aligned, banks 2-way)

__launch_bounds__(512)
__global__ void gemm_k(const unsigned short* __restrict__ embn, const float* __restrict__ Kp,
                       const float* __restrict__ cninv, const int* __restrict__ labels,
                       const float* __restrict__ ctm, const float* __restrict__ ft,
                       const float* __restrict__ newt_p, float* __restrict__ out) {
  __shared__ __align__(16) unsigned short Alds[B_N * PAD];  // 40960 B
  __shared__ __align__(16) unsigned short Blds[BN * PAD];   // 5120 B
  __shared__ int   slab[B_N];
  __shared__ float sctm[B_N];
  __shared__ float sft[B_N];

  const int t = threadIdx.x;
  const int j0 = blockIdx.x * BN;

  // per-row params into LDS (512 threads, 512 rows)
  slab[t] = labels[t];
  sctm[t] = ctm[t];
  sft[t]  = ft[t];

  const int l = t & 63, w = t >> 6;
  const int wr = w >> 1, wc = w & 1;
  const int lq = l >> 4, lr = l & 15;

  const float newt = *newt_p;
  const int jn0 = j0 + wc * 32 + lr;
  const int jn1 = jn0 + 16;
  const float cn0 = (jn0 < C_N) ? cninv[jn0] : 0.f;
  const float cn1 = (jn1 < C_N) ? cninv[jn1] : 0.f;

  f32x4 acc[8][2];
#pragma unroll
  for (int mb = 0; mb < 8; ++mb) {
    acc[mb][0] = 0;
    acc[mb][1] = 0;
  }

  // A staging map: thread -> (row = t>>2 + 128p, 8-elem chunk (t&3)*8)
  const int arow_s = t >> 2;
  const int ac8 = (t & 3) * 8;
  // B staging map: thread -> (n = t&63, k-pairs q = t>>6 + 8p)
  const int bn = t & 63;
  const int bq = t >> 6;
  const int bj = j0 + bn;
  const bool bj_ok = (bj < C_N);

  for (int k0 = 0; k0 < D_N; k0 += BK) {
    // stage A [512][BK] bf16 (from L2-resident embn)
#pragma unroll
    for (int p = 0; p < 4; ++p) {
      int row = arow_s + 128 * p;
      uint4 v = *(const uint4*)(embn + (size_t)row * D_N + k0 + ac8);
      *(uint4*)(&Alds[row * PAD + ac8]) = v;
    }
    // stage B transposed: Blds[n][kk] = bf16(K[k0+kk][j0+n])
#pragma unroll
    for (int p = 0; p < 2; ++p) {
      int q = bq + 8 * p;  // 0..15
      int kk = 2 * q;
      float f0 = bj_ok ? Kp[(size_t)(k0 + kk) * C_N + bj] : 0.f;
      float f1 = bj_ok ? Kp[(size_t)(k0 + kk + 1) * C_N + bj] : 0.f;
      unsigned u0 = f2bf(f0);
      unsigned u1 = f2bf(f1);
      *(unsigned*)(&Blds[bn * PAD + kk]) = u0 | (u1 << 16);
    }
    __syncthreads();

    short8 a[8];
#pragma unroll
    for (int mb = 0; mb < 8; ++mb) {
      int arow = wr * 128 + mb * 16 + lr;
      a[mb] = *(const short8*)(&Alds[arow * PAD + lq * 8]);
    }
    short8 b0 = *(const short8*)(&Blds[(wc * 32 + lr) * PAD + lq * 8]);
    short8 b1 = *(const short8*)(&Blds[(wc * 32 + 16 + lr) * PAD + lq * 8]);
#pragma unroll
    for (int mb = 0; mb < 8; ++mb) {
      acc[mb][0] = __builtin_amdgcn_mfma_f32_16x16x32_bf16(a[mb], b0, acc[mb][0], 0, 0, 0);
      acc[mb][1] = __builtin_amdgcn_mfma_f32_16x16x32_bf16(a[mb], b1, acc[mb][1], 0, 0, 0);
    }
    __syncthreads();
  }

  // epilogue: c/d layout col = lane&15, row = (lane>>4)*4 + r
#pragma unroll
  for (int mb = 0; mb < 8; ++mb) {
    int ibase = wr * 128 + mb * 16 + 4 * lq;
#pragma unroll
    for (int r = 0; r < 4; ++r) {
      int i = ibase + r;
      int lab = slab[i];
      float cm = sctm[i];
      float f = sft[i];
      {
        float c = acc[mb][0][r] * cn0;
        c = fminf(fmaxf(c, -1.f), 1.f);
        float o = (c > cm) ? c * (newt + c) : c;
        o = (jn0 == lab) ? f : o;
        if (jn0 < C_N) out[(size_t)i * C_N + jn0] = o * S_F;
      }
      {
        float c = acc[mb][1][r] * cn1;
        c = fminf(fmaxf(c, -1.f), 1.f);
        float o = (c > cm) ? c * (newt + c) : c;
        o = (jn1 == lab) ? f : o;
        if (jn1 < C_N) out[(size_t)i * C_N + jn1] = o * S_F;
      }
    }
  }
}

// ---------------- launch -----------------------------------------------------
extern "C" void kernel_launch(void* const* d_in, const int* in_sizes, int n_in,
                              void* d_out, int out_size, void* d_ws, size_t ws_size,
                              hipStream_t stream) {
  (void)in_sizes; (void)n_in; (void)out_size; (void)ws_size;
  const float* emb = (const float*)d_in[0];
  const int* labels = (const int*)d_in[1];
  const float* Kp = (const float*)d_in[2];
  const float* t_in = (const float*)d_in[3];
  float* out = (float*)d_out;

  char* w = (char*)d_ws;
  unsigned short* embn = (unsigned short*)(w + 0);            // 524288 B
  float* cninv = (float*)(w + 524288);                        // 400000 B
  float4* part = (float4*)(w + 924288);                       // 3200000 B
  float* target = (float*)(w + 4124288);                      // 2048 B
  float* ctm    = (float*)(w + 4126336);                      // 2048 B
  float* ft     = (float*)(w + 4128384);                      // 2048 B
  float* rinv   = (float*)(w + 4130432);                      // 2048 B
  float* newt   = (float*)(w + 4132480);                      // 4 B

  dim3 cg((JV + 255) / 256, DSPLIT);
  colnorm_part_k<<<cg, 256, 0, stream>>>(Kp, part);
  colnorm_fin_k<<<(JV + 255) / 256, 256, 0, stream>>>(part, (float4*)cninv);
  embnorm_k<<<B_N, 128, 0, stream>>>(emb, embn, rinv);
  target_k<<<B_N, 256, 0, stream>>>(emb, Kp, cninv, rinv, labels, target, ctm, ft);
  newt_k<<<1, 512, 0, stream>>>(target, t_in, newt);
  gemm_k<<<(C_N + BN - 1) / BN, 512, 0, stream>>>(embn, Kp, cninv, labels, ctm, ft, newt, out);
}